// Round 1
// baseline (1370.323 us; speedup 1.0000x reference)
//
#include <hip/hip_runtime.h>
#include <math.h>

#define NF 128   // feature/hidden dim (F == H == 128)

// ---------- setup kernels ----------

__global__ void k_init(int* cnt, float* pooled, float* gcount, int n, int gtot, int g) {
    int i = blockIdx.x * blockDim.x + threadIdx.x;
    if (i < n)    cnt[i] = 1;           // self-loop contributes 1 to degree
    if (i < gtot) pooled[i] = 0.f;
    if (i < g)    gcount[i] = 0.f;
}

__global__ void k_deg(const int* __restrict__ ei, int* cnt, int E) {
    int e = blockIdx.x * blockDim.x + threadIdx.x;
    if (e < E) atomicAdd(&cnt[ei[E + e]], 1);   // dst row of edge_index
}

__global__ void k_dinv(const int* __restrict__ cnt, float* dinv, int n) {
    int i = blockIdx.x * blockDim.x + threadIdx.x;
    if (i < n) dinv[i] = 1.0f / sqrtf((float)cnt[i]);
}

// Block-level exclusive scan (256/block), emits block sums.
__global__ void k_scan1(const int* __restrict__ cnt, int* offs, int* bsum, int n) {
    __shared__ int s[256];
    int t = threadIdx.x;
    int i = blockIdx.x * 256 + t;
    int v = (i < n) ? cnt[i] : 0;
    s[t] = v;
    for (int d = 1; d < 256; d <<= 1) {
        __syncthreads();
        int add = (t >= d) ? s[t - d] : 0;
        __syncthreads();
        s[t] += add;
    }
    __syncthreads();
    if (i < n) offs[i] = s[t] - v;          // exclusive
    if (t == 255) bsum[blockIdx.x] = s[255]; // block total
}

// Single-block exclusive scan of block sums (nb <= 512).
__global__ void k_scan2(int* bsum, int nb) {
    __shared__ int s[512];
    int t = threadIdx.x;
    int v = (t < nb) ? bsum[t] : 0;
    s[t] = v;
    for (int d = 1; d < 512; d <<= 1) {
        __syncthreads();
        int add = (t >= d) ? s[t - d] : 0;
        __syncthreads();
        s[t] += add;
    }
    __syncthreads();
    if (t < nb) bsum[t] = s[t] - v;         // exclusive
}

__global__ void k_scan3(int* offs, const int* __restrict__ bsum, int* cursor, int n, int total) {
    int i = blockIdx.x * 256 + threadIdx.x;
    if (i < n) {
        int o = offs[i] + bsum[blockIdx.x];
        offs[i] = o;
        cursor[i] = o;
    }
    if (i == 0) offs[n] = total;
}

// Scatter edges (+ self loops) into dst-sorted CSR with precomputed norm.
__global__ void k_fill(const int* __restrict__ ei, const float* __restrict__ dinv,
                       int* cursor, int* srcS, float* nrmS, int E, int n) {
    int t = blockIdx.x * blockDim.x + threadIdx.x;
    if (t < E) {
        int s = ei[t], d = ei[E + t];
        int p = atomicAdd(&cursor[d], 1);
        srcS[p] = s;
        nrmS[p] = dinv[s] * dinv[d];
    } else if (t < E + n) {
        int i = t - E;
        int p = atomicAdd(&cursor[i], 1);
        float di = dinv[i];
        srcS[p] = i;
        nrmS[p] = di * di;
    }
}

// ---------- per-layer kernels ----------

// agg[node][:] = sum_{e in CSR row} norm[e] * hin[src[e]][:]
// one block (128 threads = 2 waves) per node, 1 channel/thread
__global__ void k_spmm(const float* __restrict__ hin, const int* __restrict__ offs,
                       const int* __restrict__ srcS, const float* __restrict__ nrmS,
                       float* __restrict__ agg) {
    int node = blockIdx.x;
    int ch = threadIdx.x;
    int b = offs[node], e = offs[node + 1];
    float acc = 0.f;
    for (int j = b; j < e; ++j) {
        int s = srcS[j];
        float w = nrmS[j];
        acc += w * hin[s * NF + ch];
    }
    agg[node * NF + ch] = acc;
}

// out[i][:] = relu(A[i][:] @ W + b), A: n x 128, W: 128 x 128 row-major.
// 64-row tile per 256-thread block; A staged in LDS stride 132
// (16B-aligned rows; inner 8-row reads hit 8 distinct banks; the
// half-wave alias is the free 2-way case).
__global__ __launch_bounds__(256) void k_gemm_bias_relu(
        const float* __restrict__ A, const float* __restrict__ W,
        const float* __restrict__ bias, float* __restrict__ out, int n) {
    __shared__ float As[64 * 132];
    int tid = threadIdx.x;
    int row0 = blockIdx.x * 64;

    #pragma unroll
    for (int i = 0; i < 8; ++i) {
        int idx = tid + i * 256;          // 0..2047 float4 slots
        int r = idx >> 5, c4 = (idx & 31) << 2;
        int gr = row0 + r;
        float4 v = make_float4(0.f, 0.f, 0.f, 0.f);
        if (gr < n) v = *(const float4*)(A + gr * NF + c4);
        *(float4*)(As + r * 132 + c4) = v;
    }
    __syncthreads();

    int cg = tid & 31;        // 4-col group
    int rb = tid >> 5;        // 8-row group: rows rb*8 .. rb*8+7
    float4 acc[8];
    #pragma unroll
    for (int j = 0; j < 8; ++j) acc[j] = make_float4(0.f, 0.f, 0.f, 0.f);

    const float* Wp = W + (cg << 2);
    const float* Ap = As + rb * 8 * 132;
    #pragma unroll 4
    for (int k = 0; k < 128; ++k) {
        float4 w = *(const float4*)(Wp + k * NF);
        #pragma unroll
        for (int j = 0; j < 8; ++j) {
            float a = Ap[j * 132 + k];
            acc[j].x += a * w.x;
            acc[j].y += a * w.y;
            acc[j].z += a * w.z;
            acc[j].w += a * w.w;
        }
    }

    float4 bv = *(const float4*)(bias + (cg << 2));
    #pragma unroll
    for (int j = 0; j < 8; ++j) {
        int gr = row0 + rb * 8 + j;
        if (gr < n) {
            float4 o;
            o.x = fmaxf(acc[j].x + bv.x, 0.f);
            o.y = fmaxf(acc[j].y + bv.y, 0.f);
            o.z = fmaxf(acc[j].z + bv.z, 0.f);
            o.w = fmaxf(acc[j].w + bv.w, 0.f);
            *(float4*)(out + gr * NF + (cg << 2)) = o;
        }
    }
}

// ---------- pooling / head ----------

__global__ void k_pool(const float* __restrict__ h, const int* __restrict__ batch,
                       float* pooled, float* gcount) {
    int i = blockIdx.x;
    int ch = threadIdx.x;
    int g = batch[i];
    atomicAdd(&pooled[g * NF + ch], h[i * NF + ch]);
    if (ch == 0) atomicAdd(&gcount[g], 1.f);
}

__global__ void k_final(const float* __restrict__ pooled, const float* __restrict__ gcount,
                        const float* __restrict__ linW, const float* __restrict__ linb,
                        float* __restrict__ outp, int G2) {
    int t = blockIdx.x * blockDim.x + threadIdx.x;
    if (t >= G2) return;
    int g = t >> 1, j = t & 1;
    float s = 0.f;
    #pragma unroll 8
    for (int c = 0; c < NF; ++c) s += pooled[g * NF + c] * linW[c * 2 + j];
    outp[t] = s / fmaxf(gcount[g], 1.f) + linb[j];
}

// ---------- launcher ----------

extern "C" void kernel_launch(void* const* d_in, const int* in_sizes, int n_in,
                              void* d_out, int out_size, void* d_ws, size_t ws_size,
                              hipStream_t stream) {
    const float* x     = (const float*)d_in[0];
    const int*   ei    = (const int*)d_in[1];
    const int*   batch = (const int*)d_in[2];
    const float* Wl[4] = {(const float*)d_in[3], (const float*)d_in[5],
                          (const float*)d_in[7], (const float*)d_in[9]};
    const float* bl[4] = {(const float*)d_in[4], (const float*)d_in[6],
                          (const float*)d_in[8], (const float*)d_in[10]};
    const float* linW  = (const float*)d_in[11];
    const float* linb  = (const float*)d_in[12];
    float* out = (float*)d_out;

    const int N  = in_sizes[2];
    const int E  = in_sizes[1] / 2;
    const int G  = out_size / 2;
    const int Et = E + N;

    // carve workspace (256B-aligned slices)
    char* p = (char*)d_ws;
    auto carve = [&](size_t bytes) -> char* {
        char* r = p;
        p += (bytes + 255) & ~(size_t)255;
        return r;
    };
    int*   cnt    = (int*)  carve((size_t)N * 4);
    float* dinv   = (float*)carve((size_t)N * 4);
    int*   offs   = (int*)  carve((size_t)(N + 1) * 4);
    int*   cursor = (int*)  carve((size_t)N * 4);
    int*   bsum   = (int*)  carve(512 * 4);
    int*   srcS   = (int*)  carve((size_t)Et * 4);
    float* nrmS   = (float*)carve((size_t)Et * 4);
    float* bufA   = (float*)carve((size_t)N * NF * 4);   // h
    float* bufB   = (float*)carve((size_t)N * NF * 4);   // agg
    float* pooled = (float*)carve((size_t)G * NF * 4);
    float* gcount = (float*)carve((size_t)G * 4);

    int initN = (G * NF > N) ? G * NF : N;
    k_init<<<(initN + 255) / 256, 256, 0, stream>>>(cnt, pooled, gcount, N, G * NF, G);
    k_deg<<<(E + 255) / 256, 256, 0, stream>>>(ei, cnt, E);
    k_dinv<<<(N + 255) / 256, 256, 0, stream>>>(cnt, dinv, N);

    int nb = (N + 255) / 256;   // 391 <= 512
    k_scan1<<<nb, 256, 0, stream>>>(cnt, offs, bsum, N);
    k_scan2<<<1, 512, 0, stream>>>(bsum, nb);
    k_scan3<<<nb, 256, 0, stream>>>(offs, bsum, cursor, N, Et);
    k_fill<<<(Et + 255) / 256, 256, 0, stream>>>(ei, dinv, cursor, srcS, nrmS, E, N);

    const float* hin = x;
    for (int l = 0; l < 4; ++l) {
        k_spmm<<<N, NF, 0, stream>>>(hin, offs, srcS, nrmS, bufB);
        k_gemm_bias_relu<<<(N + 63) / 64, 256, 0, stream>>>(bufB, Wl[l], bl[l], bufA, N);
        hin = bufA;
    }

    k_pool<<<N, NF, 0, stream>>>(bufA, batch, pooled, gcount);
    k_final<<<(2 * G + 255) / 256, 256, 0, stream>>>(pooled, gcount, linW, linb, out, 2 * G);
}

// Round 2
// 1004.064 us; speedup vs baseline: 1.3648x; 1.3648x over previous
//
#include <hip/hip_runtime.h>
#include <math.h>

#define NF 128   // feature/hidden dim (F == H == 128)

// ---------- setup kernels ----------

__global__ void k_init(int* cnt, int n) {
    int i = blockIdx.x * blockDim.x + threadIdx.x;
    if (i < n) cnt[i] = 1;              // self-loop contributes 1 to degree
}

__global__ void k_deg(const int* __restrict__ ei, int* cnt, int E) {
    int e = blockIdx.x * blockDim.x + threadIdx.x;
    if (e < E) atomicAdd(&cnt[ei[E + e]], 1);   // dst row of edge_index
}

__global__ void k_dinv(const int* __restrict__ cnt, float* dinv, int n) {
    int i = blockIdx.x * blockDim.x + threadIdx.x;
    if (i < n) dinv[i] = 1.0f / sqrtf((float)cnt[i]);
}

// Block-level exclusive scan (256/block), emits block sums.
__global__ void k_scan1(const int* __restrict__ cnt, int* offs, int* bsum, int n) {
    __shared__ int s[256];
    int t = threadIdx.x;
    int i = blockIdx.x * 256 + t;
    int v = (i < n) ? cnt[i] : 0;
    s[t] = v;
    for (int d = 1; d < 256; d <<= 1) {
        __syncthreads();
        int add = (t >= d) ? s[t - d] : 0;
        __syncthreads();
        s[t] += add;
    }
    __syncthreads();
    if (i < n) offs[i] = s[t] - v;          // exclusive
    if (t == 255) bsum[blockIdx.x] = s[255]; // block total
}

// Single-block exclusive scan of block sums (nb <= 512).
__global__ void k_scan2(int* bsum, int nb) {
    __shared__ int s[512];
    int t = threadIdx.x;
    int v = (t < nb) ? bsum[t] : 0;
    s[t] = v;
    for (int d = 1; d < 512; d <<= 1) {
        __syncthreads();
        int add = (t >= d) ? s[t - d] : 0;
        __syncthreads();
        s[t] += add;
    }
    __syncthreads();
    if (t < nb) bsum[t] = s[t] - v;         // exclusive
}

__global__ void k_scan3(int* offs, const int* __restrict__ bsum, int* cursor, int n, int total) {
    int i = blockIdx.x * 256 + threadIdx.x;
    if (i < n) {
        int o = offs[i] + bsum[blockIdx.x];
        offs[i] = o;
        cursor[i] = o;
    }
    if (i == 0) offs[n] = total;
}

// Scatter edges (+ self loops) into dst-sorted CSR; pack (src, norm) in int2.
__global__ void k_fill(const int* __restrict__ ei, const float* __restrict__ dinv,
                       int* cursor, int2* pk, int E, int n) {
    int t = blockIdx.x * blockDim.x + threadIdx.x;
    if (t < E) {
        int s = ei[t], d = ei[E + t];
        int p = atomicAdd(&cursor[d], 1);
        pk[p] = make_int2(s, __float_as_int(dinv[s] * dinv[d]));
    } else if (t < E + n) {
        int i = t - E;
        int p = atomicAdd(&cursor[i], 1);
        float di = dinv[i];
        pk[p] = make_int2(i, __float_as_int(di * di));
    }
}

// graph boundaries in sorted batch: gstart[g] = lower_bound(batch, g)
__global__ void k_bounds(const int* __restrict__ batch, int* gstart, int N, int G) {
    int g = blockIdx.x * blockDim.x + threadIdx.x;
    if (g > G) return;
    int lo = 0, hi = N;
    while (lo < hi) {
        int mid = (lo + hi) >> 1;
        if (batch[mid] < g) lo = mid + 1; else hi = mid;
    }
    gstart[g] = lo;
}

// ---------- per-layer kernels ----------

// agg[node][:] = sum_{e in CSR row} norm[e] * hin[src[e]][:]
// 32 lanes per node (float4/lane), 8 nodes per 256-thread block.
// Edges unrolled x4 -> 4 independent 16B gathers in flight per lane.
__global__ __launch_bounds__(256) void k_spmm(const float* __restrict__ hin,
        const int* __restrict__ offs, const int2* __restrict__ pk,
        float* __restrict__ agg, int n) {
    int node = blockIdx.x * 8 + (threadIdx.x >> 5);
    if (node >= n) return;
    int c4 = (threadIdx.x & 31) << 2;
    int b = offs[node], e = offs[node + 1];
    float4 acc = make_float4(0.f, 0.f, 0.f, 0.f);
    int j = b;
    for (; j + 4 <= e; j += 4) {
        int2 p0 = pk[j], p1 = pk[j + 1], p2 = pk[j + 2], p3 = pk[j + 3];
        float4 r0 = *(const float4*)(hin + (size_t)p0.x * NF + c4);
        float4 r1 = *(const float4*)(hin + (size_t)p1.x * NF + c4);
        float4 r2 = *(const float4*)(hin + (size_t)p2.x * NF + c4);
        float4 r3 = *(const float4*)(hin + (size_t)p3.x * NF + c4);
        float w0 = __int_as_float(p0.y), w1 = __int_as_float(p1.y);
        float w2 = __int_as_float(p2.y), w3 = __int_as_float(p3.y);
        acc.x += w0 * r0.x + w1 * r1.x + w2 * r2.x + w3 * r3.x;
        acc.y += w0 * r0.y + w1 * r1.y + w2 * r2.y + w3 * r3.y;
        acc.z += w0 * r0.z + w1 * r1.z + w2 * r2.z + w3 * r3.z;
        acc.w += w0 * r0.w + w1 * r1.w + w2 * r2.w + w3 * r3.w;
    }
    for (; j < e; ++j) {
        int2 p = pk[j];
        float4 r = *(const float4*)(hin + (size_t)p.x * NF + c4);
        float w = __int_as_float(p.y);
        acc.x += w * r.x; acc.y += w * r.y; acc.z += w * r.z; acc.w += w * r.w;
    }
    *(float4*)(agg + (size_t)node * NF + c4) = acc;
}

// out[i][:] = relu(A[i][:] @ W + b), A: n x 128, W: 128 x 128 row-major.
// 64-row tile per 256-thread block; A staged in LDS stride 132 (16B-aligned
// rows: 132*4B = 33*16B). k unrolled x4 so LDS reads are ds_read_b128.
__global__ __launch_bounds__(256) void k_gemm_bias_relu(
        const float* __restrict__ A, const float* __restrict__ W,
        const float* __restrict__ bias, float* __restrict__ out, int n) {
    __shared__ float As[64 * 132];
    int tid = threadIdx.x;
    int row0 = blockIdx.x * 64;

    #pragma unroll
    for (int i = 0; i < 8; ++i) {
        int idx = tid + i * 256;          // 0..2047 float4 slots
        int r = idx >> 5, c4 = (idx & 31) << 2;
        int gr = row0 + r;
        float4 v = make_float4(0.f, 0.f, 0.f, 0.f);
        if (gr < n) v = *(const float4*)(A + gr * NF + c4);
        *(float4*)(As + r * 132 + c4) = v;
    }
    __syncthreads();

    int cg = tid & 31;        // 4-col group
    int rb = tid >> 5;        // 8-row group: rows rb*8 .. rb*8+7
    float4 acc[8];
    #pragma unroll
    for (int j = 0; j < 8; ++j) acc[j] = make_float4(0.f, 0.f, 0.f, 0.f);

    const float* Wp = W + (cg << 2);
    const float* Ap = As + rb * 8 * 132;
    for (int k = 0; k < 128; k += 4) {
        float4 w0 = *(const float4*)(Wp + (k + 0) * NF);
        float4 w1 = *(const float4*)(Wp + (k + 1) * NF);
        float4 w2 = *(const float4*)(Wp + (k + 2) * NF);
        float4 w3 = *(const float4*)(Wp + (k + 3) * NF);
        #pragma unroll
        for (int j = 0; j < 8; ++j) {
            float4 a = *(const float4*)(Ap + j * 132 + k);
            acc[j].x += a.x * w0.x + a.y * w1.x + a.z * w2.x + a.w * w3.x;
            acc[j].y += a.x * w0.y + a.y * w1.y + a.z * w2.y + a.w * w3.y;
            acc[j].z += a.x * w0.z + a.y * w1.z + a.z * w2.z + a.w * w3.z;
            acc[j].w += a.x * w0.w + a.y * w1.w + a.z * w2.w + a.w * w3.w;
        }
    }

    float4 bv = *(const float4*)(bias + (cg << 2));
    #pragma unroll
    for (int j = 0; j < 8; ++j) {
        int gr = row0 + rb * 8 + j;
        if (gr < n) {
            float4 o;
            o.x = fmaxf(acc[j].x + bv.x, 0.f);
            o.y = fmaxf(acc[j].y + bv.y, 0.f);
            o.z = fmaxf(acc[j].z + bv.z, 0.f);
            o.w = fmaxf(acc[j].w + bv.w, 0.f);
            *(float4*)(out + gr * NF + (cg << 2)) = o;
        }
    }
}

// ---------- fused pool + head (batch is sorted -> contiguous ranges) ----------

__global__ __launch_bounds__(128) void k_poolfinal(const float* __restrict__ h,
        const int* __restrict__ gstart, const float* __restrict__ linW,
        const float* __restrict__ linb, float* __restrict__ outp) {
    int g = blockIdx.x;
    int ch = threadIdx.x;
    int b = gstart[g], e = gstart[g + 1];
    float s = 0.f;
    for (int i = b; i < e; ++i) s += h[(size_t)i * NF + ch];
    float inv = 1.0f / fmaxf((float)(e - b), 1.0f);
    float v0 = s * linW[ch * 2 + 0];
    float v1 = s * linW[ch * 2 + 1];
    #pragma unroll
    for (int d = 32; d > 0; d >>= 1) {
        v0 += __shfl_down(v0, d);
        v1 += __shfl_down(v1, d);
    }
    __shared__ float sv[4];
    if ((ch & 63) == 0) { sv[(ch >> 6) * 2] = v0; sv[(ch >> 6) * 2 + 1] = v1; }
    __syncthreads();
    if (ch == 0) {
        outp[g * 2 + 0] = (sv[0] + sv[2]) * inv + linb[0];
        outp[g * 2 + 1] = (sv[1] + sv[3]) * inv + linb[1];
    }
}

// ---------- launcher ----------

extern "C" void kernel_launch(void* const* d_in, const int* in_sizes, int n_in,
                              void* d_out, int out_size, void* d_ws, size_t ws_size,
                              hipStream_t stream) {
    const float* x     = (const float*)d_in[0];
    const int*   ei    = (const int*)d_in[1];
    const int*   batch = (const int*)d_in[2];
    const float* Wl[4] = {(const float*)d_in[3], (const float*)d_in[5],
                          (const float*)d_in[7], (const float*)d_in[9]};
    const float* bl[4] = {(const float*)d_in[4], (const float*)d_in[6],
                          (const float*)d_in[8], (const float*)d_in[10]};
    const float* linW  = (const float*)d_in[11];
    const float* linb  = (const float*)d_in[12];
    float* out = (float*)d_out;

    const int N  = in_sizes[2];
    const int E  = in_sizes[1] / 2;
    const int G  = out_size / 2;
    const int Et = E + N;

    // carve workspace (256B-aligned slices)
    char* p = (char*)d_ws;
    auto carve = [&](size_t bytes) -> char* {
        char* r = p;
        p += (bytes + 255) & ~(size_t)255;
        return r;
    };
    int*   cnt    = (int*)  carve((size_t)N * 4);
    float* dinv   = (float*)carve((size_t)N * 4);
    int*   offs   = (int*)  carve((size_t)(N + 1) * 4);
    int*   cursor = (int*)  carve((size_t)N * 4);
    int*   bsum   = (int*)  carve(512 * 4);
    int2*  pk     = (int2*) carve((size_t)Et * 8);
    float* bufA   = (float*)carve((size_t)N * NF * 4);   // h
    float* bufB   = (float*)carve((size_t)N * NF * 4);   // agg
    int*   gstart = (int*)  carve((size_t)(G + 1) * 4);

    k_init<<<(N + 255) / 256, 256, 0, stream>>>(cnt, N);
    k_deg<<<(E + 255) / 256, 256, 0, stream>>>(ei, cnt, E);
    k_dinv<<<(N + 255) / 256, 256, 0, stream>>>(cnt, dinv, N);

    int nb = (N + 255) / 256;   // 391 <= 512
    k_scan1<<<nb, 256, 0, stream>>>(cnt, offs, bsum, N);
    k_scan2<<<1, 512, 0, stream>>>(bsum, nb);
    k_scan3<<<nb, 256, 0, stream>>>(offs, bsum, cursor, N, Et);
    k_fill<<<(Et + 255) / 256, 256, 0, stream>>>(ei, dinv, cursor, pk, E, N);
    k_bounds<<<(G + 256) / 256, 256, 0, stream>>>(batch, gstart, N, G);

    const float* hin = x;
    for (int l = 0; l < 4; ++l) {
        k_spmm<<<(N + 7) / 8, 256, 0, stream>>>(hin, offs, pk, bufB, N);
        k_gemm_bias_relu<<<(N + 63) / 64, 256, 0, stream>>>(bufB, Wl[l], bl[l], bufA, N);
        hin = bufA;
    }

    k_poolfinal<<<G, 128, 0, stream>>>(bufA, gstart, linW, linb, out);
}

// Round 3
// 943.826 us; speedup vs baseline: 1.4519x; 1.0638x over previous
//
#include <hip/hip_runtime.h>
#include <math.h>

#define NF 128   // feature/hidden dim (F == H == 128)

// ---------- setup kernels ----------

__global__ void k_init(int* cnt, int n) {
    int i = blockIdx.x * blockDim.x + threadIdx.x;
    if (i < n) cnt[i] = 1;              // self-loop contributes 1 to degree
}

__global__ void k_deg(const int* __restrict__ ei, int* cnt, int E) {
    int e = blockIdx.x * blockDim.x + threadIdx.x;
    if (e < E) atomicAdd(&cnt[ei[E + e]], 1);   // dst row of edge_index
}

__global__ void k_dinv(const int* __restrict__ cnt, float* dinv, int n) {
    int i = blockIdx.x * blockDim.x + threadIdx.x;
    if (i < n) dinv[i] = 1.0f / sqrtf((float)cnt[i]);
}

// Block-level exclusive scan (256/block), emits block sums.
__global__ void k_scan1(const int* __restrict__ cnt, int* offs, int* bsum, int n) {
    __shared__ int s[256];
    int t = threadIdx.x;
    int i = blockIdx.x * 256 + t;
    int v = (i < n) ? cnt[i] : 0;
    s[t] = v;
    for (int d = 1; d < 256; d <<= 1) {
        __syncthreads();
        int add = (t >= d) ? s[t - d] : 0;
        __syncthreads();
        s[t] += add;
    }
    __syncthreads();
    if (i < n) offs[i] = s[t] - v;          // exclusive
    if (t == 255) bsum[blockIdx.x] = s[255]; // block total
}

// Single-block exclusive scan of block sums (nb <= 512).
__global__ void k_scan2(int* bsum, int nb) {
    __shared__ int s[512];
    int t = threadIdx.x;
    int v = (t < nb) ? bsum[t] : 0;
    s[t] = v;
    for (int d = 1; d < 512; d <<= 1) {
        __syncthreads();
        int add = (t >= d) ? s[t - d] : 0;
        __syncthreads();
        s[t] += add;
    }
    __syncthreads();
    if (t < nb) bsum[t] = s[t] - v;         // exclusive
}

__global__ void k_scan3(int* offs, const int* __restrict__ bsum, int* cursor, int n, int total) {
    int i = blockIdx.x * 256 + threadIdx.x;
    if (i < n) {
        int o = offs[i] + bsum[blockIdx.x];
        offs[i] = o;
        cursor[i] = o;
    }
    if (i == 0) offs[n] = total;
}

// Scatter edges (+ self loops) into dst-sorted CSR; pack (src, norm) in int2.
__global__ void k_fill(const int* __restrict__ ei, const float* __restrict__ dinv,
                       int* cursor, int2* pk, int E, int n) {
    int t = blockIdx.x * blockDim.x + threadIdx.x;
    if (t < E) {
        int s = ei[t], d = ei[E + t];
        int p = atomicAdd(&cursor[d], 1);
        pk[p] = make_int2(s, __float_as_int(dinv[s] * dinv[d]));
    } else if (t < E + n) {
        int i = t - E;
        int p = atomicAdd(&cursor[i], 1);
        float di = dinv[i];
        pk[p] = make_int2(i, __float_as_int(di * di));
    }
}

// graph boundaries in sorted batch: gstart[g] = lower_bound(batch, g)
__global__ void k_bounds(const int* __restrict__ batch, int* gstart, int N, int G) {
    int g = blockIdx.x * blockDim.x + threadIdx.x;
    if (g > G) return;
    int lo = 0, hi = N;
    while (lo < hi) {
        int mid = (lo + hi) >> 1;
        if (batch[mid] < g) lo = mid + 1; else hi = mid;
    }
    gstart[g] = lo;
}

// ---------- fused layer kernel: SpMM-aggregate into LDS, then GEMM+bias+ReLU ----------
// out[i][:] = relu( (sum_e norm*hin[src]) @ W + b ) for a 64-row tile per block.
// Gather phase: 8 half-wave groups x 8 nodes each, float4/lane, edges unrolled x8.
// GEMM phase: As reads are broadcast within each 32-lane group (conflict-free),
// stride 128 (no pad) keeps LDS at 32KB -> 5 blocks/CU.
__global__ __launch_bounds__(256) void k_fused(
        const float* __restrict__ hin, const int* __restrict__ offs,
        const int2* __restrict__ pk, const float* __restrict__ W,
        const float* __restrict__ bias, float* __restrict__ out, int n) {
    __shared__ float As[64 * 128];
    int tid = threadIdx.x;
    int row0 = blockIdx.x * 64;
    int grp = tid >> 5;          // 0..7: 32-lane group
    int c4 = (tid & 31) << 2;    // float4 column offset

    // ---- gather/aggregate phase ----
    #pragma unroll
    for (int i = 0; i < 8; ++i) {
        int r = grp * 8 + i;
        int node = row0 + r;
        float4 acc = make_float4(0.f, 0.f, 0.f, 0.f);
        if (node < n) {
            int b = offs[node], e = offs[node + 1];
            int j = b;
            for (; j + 8 <= e; j += 8) {
                int2 p0 = pk[j],     p1 = pk[j + 1], p2 = pk[j + 2], p3 = pk[j + 3];
                int2 p4 = pk[j + 4], p5 = pk[j + 5], p6 = pk[j + 6], p7 = pk[j + 7];
                float4 r0 = *(const float4*)(hin + (size_t)p0.x * NF + c4);
                float4 r1 = *(const float4*)(hin + (size_t)p1.x * NF + c4);
                float4 r2 = *(const float4*)(hin + (size_t)p2.x * NF + c4);
                float4 r3 = *(const float4*)(hin + (size_t)p3.x * NF + c4);
                float4 r4 = *(const float4*)(hin + (size_t)p4.x * NF + c4);
                float4 r5 = *(const float4*)(hin + (size_t)p5.x * NF + c4);
                float4 r6 = *(const float4*)(hin + (size_t)p6.x * NF + c4);
                float4 r7 = *(const float4*)(hin + (size_t)p7.x * NF + c4);
                float w0 = __int_as_float(p0.y), w1 = __int_as_float(p1.y);
                float w2 = __int_as_float(p2.y), w3 = __int_as_float(p3.y);
                float w4 = __int_as_float(p4.y), w5 = __int_as_float(p5.y);
                float w6 = __int_as_float(p6.y), w7 = __int_as_float(p7.y);
                acc.x += w0*r0.x + w1*r1.x + w2*r2.x + w3*r3.x
                       + w4*r4.x + w5*r5.x + w6*r6.x + w7*r7.x;
                acc.y += w0*r0.y + w1*r1.y + w2*r2.y + w3*r3.y
                       + w4*r4.y + w5*r5.y + w6*r6.y + w7*r7.y;
                acc.z += w0*r0.z + w1*r1.z + w2*r2.z + w3*r3.z
                       + w4*r4.z + w5*r5.z + w6*r6.z + w7*r7.z;
                acc.w += w0*r0.w + w1*r1.w + w2*r2.w + w3*r3.w
                       + w4*r4.w + w5*r5.w + w6*r6.w + w7*r7.w;
            }
            for (; j < e; ++j) {
                int2 p = pk[j];
                float4 rr = *(const float4*)(hin + (size_t)p.x * NF + c4);
                float w = __int_as_float(p.y);
                acc.x += w * rr.x; acc.y += w * rr.y;
                acc.z += w * rr.z; acc.w += w * rr.w;
            }
        }
        *(float4*)(As + r * 128 + c4) = acc;
    }
    __syncthreads();

    // ---- GEMM + bias + ReLU phase ----
    int cg = tid & 31;        // 4-col group of W
    int rb = tid >> 5;        // 8-row group: rows rb*8 .. rb*8+7
    float4 acc[8];
    #pragma unroll
    for (int j = 0; j < 8; ++j) acc[j] = make_float4(0.f, 0.f, 0.f, 0.f);

    const float* Wp = W + (cg << 2);
    const float* Ap = As + rb * 8 * 128;
    for (int k = 0; k < 128; k += 4) {
        float4 w0 = *(const float4*)(Wp + (k + 0) * NF);
        float4 w1 = *(const float4*)(Wp + (k + 1) * NF);
        float4 w2 = *(const float4*)(Wp + (k + 2) * NF);
        float4 w3 = *(const float4*)(Wp + (k + 3) * NF);
        #pragma unroll
        for (int j = 0; j < 8; ++j) {
            float4 a = *(const float4*)(Ap + j * 128 + k);
            acc[j].x += a.x * w0.x + a.y * w1.x + a.z * w2.x + a.w * w3.x;
            acc[j].y += a.x * w0.y + a.y * w1.y + a.z * w2.y + a.w * w3.y;
            acc[j].z += a.x * w0.z + a.y * w1.z + a.z * w2.z + a.w * w3.z;
            acc[j].w += a.x * w0.w + a.y * w1.w + a.z * w2.w + a.w * w3.w;
        }
    }

    float4 bv = *(const float4*)(bias + (cg << 2));
    #pragma unroll
    for (int j = 0; j < 8; ++j) {
        int gr = row0 + rb * 8 + j;
        if (gr < n) {
            float4 o;
            o.x = fmaxf(acc[j].x + bv.x, 0.f);
            o.y = fmaxf(acc[j].y + bv.y, 0.f);
            o.z = fmaxf(acc[j].z + bv.z, 0.f);
            o.w = fmaxf(acc[j].w + bv.w, 0.f);
            *(float4*)(out + (size_t)gr * NF + (cg << 2)) = o;
        }
    }
}

// ---------- fused pool + head (batch is sorted -> contiguous ranges) ----------

__global__ __launch_bounds__(128) void k_poolfinal(const float* __restrict__ h,
        const int* __restrict__ gstart, const float* __restrict__ linW,
        const float* __restrict__ linb, float* __restrict__ outp) {
    int g = blockIdx.x;
    int ch = threadIdx.x;
    int b = gstart[g], e = gstart[g + 1];
    float s = 0.f;
    for (int i = b; i < e; ++i) s += h[(size_t)i * NF + ch];
    float inv = 1.0f / fmaxf((float)(e - b), 1.0f);
    float v0 = s * linW[ch * 2 + 0];
    float v1 = s * linW[ch * 2 + 1];
    #pragma unroll
    for (int d = 32; d > 0; d >>= 1) {
        v0 += __shfl_down(v0, d);
        v1 += __shfl_down(v1, d);
    }
    __shared__ float sv[4];
    if ((ch & 63) == 0) { sv[(ch >> 6) * 2] = v0; sv[(ch >> 6) * 2 + 1] = v1; }
    __syncthreads();
    if (ch == 0) {
        outp[g * 2 + 0] = (sv[0] + sv[2]) * inv + linb[0];
        outp[g * 2 + 1] = (sv[1] + sv[3]) * inv + linb[1];
    }
}

// ---------- launcher ----------

extern "C" void kernel_launch(void* const* d_in, const int* in_sizes, int n_in,
                              void* d_out, int out_size, void* d_ws, size_t ws_size,
                              hipStream_t stream) {
    const float* x     = (const float*)d_in[0];
    const int*   ei    = (const int*)d_in[1];
    const int*   batch = (const int*)d_in[2];
    const float* Wl[4] = {(const float*)d_in[3], (const float*)d_in[5],
                          (const float*)d_in[7], (const float*)d_in[9]};
    const float* bl[4] = {(const float*)d_in[4], (const float*)d_in[6],
                          (const float*)d_in[8], (const float*)d_in[10]};
    const float* linW  = (const float*)d_in[11];
    const float* linb  = (const float*)d_in[12];
    float* out = (float*)d_out;

    const int N  = in_sizes[2];
    const int E  = in_sizes[1] / 2;
    const int G  = out_size / 2;
    const int Et = E + N;

    // carve workspace (256B-aligned slices)
    char* p = (char*)d_ws;
    auto carve = [&](size_t bytes) -> char* {
        char* r = p;
        p += (bytes + 255) & ~(size_t)255;
        return r;
    };
    int*   cnt    = (int*)  carve((size_t)N * 4);
    float* dinv   = (float*)carve((size_t)N * 4);
    int*   offs   = (int*)  carve((size_t)(N + 1) * 4);
    int*   cursor = (int*)  carve((size_t)N * 4);
    int*   bsum   = (int*)  carve(512 * 4);
    int2*  pk     = (int2*) carve((size_t)Et * 8);
    float* bufA   = (float*)carve((size_t)N * NF * 4);   // h ping
    float* bufB   = (float*)carve((size_t)N * NF * 4);   // h pong
    int*   gstart = (int*)  carve((size_t)(G + 1) * 4);

    k_init<<<(N + 255) / 256, 256, 0, stream>>>(cnt, N);
    k_deg<<<(E + 255) / 256, 256, 0, stream>>>(ei, cnt, E);
    k_dinv<<<(N + 255) / 256, 256, 0, stream>>>(cnt, dinv, N);

    int nb = (N + 255) / 256;   // 391 <= 512
    k_scan1<<<nb, 256, 0, stream>>>(cnt, offs, bsum, N);
    k_scan2<<<1, 512, 0, stream>>>(bsum, nb);
    k_scan3<<<nb, 256, 0, stream>>>(offs, bsum, cursor, N, Et);
    k_fill<<<(Et + 255) / 256, 256, 0, stream>>>(ei, dinv, cursor, pk, E, N);
    k_bounds<<<(G + 256) / 256, 256, 0, stream>>>(batch, gstart, N, G);

    int ngrid = (N + 63) / 64;
    const float* hin = x;
    float* hout = bufA;
    for (int l = 0; l < 4; ++l) {
        k_fused<<<ngrid, 256, 0, stream>>>(hin, offs, pk, Wl[l], bl[l], hout, N);
        hin = hout;
        hout = (hout == bufA) ? bufB : bufA;
    }

    k_poolfinal<<<G, 128, 0, stream>>>((const float*)hin, gstart, linW, linb, out);
}